// Round 9
// baseline (151.456 us; speedup 1.0000x reference)
//
#include <hip/hip_runtime.h>

// Problem: B=16,C=64,H=32,W=32 -> N=16384 tokens; K=8192 codes.
#define DECAYF 0.99f
#define OMDF   0.01f
#define TAU    3.5e-2f   // fp16 screen: ~9-sigma pairwise (sigma~3.8e-3); candidate fixup exact f32

typedef unsigned int u32;
typedef unsigned long long u64;
typedef __attribute__((ext_vector_type(8))) _Float16 f16x8;  // 8 fp16 (4 VGPRs)
typedef __attribute__((ext_vector_type(4))) float f32x4;     // MFMA 16x16 acc

// ws layout (bytes). High-water = 5275656 (== R0 proven size).
// zfrag (2 MB, fp16 z_e in 16x16 A-frag order) lives in the out0 output
// region: written by k_prep, read by k_argmin, overwritten by k_gather.
// IDX overlays EFRAG (efrag dead after k_argmin; stream-ordered).
#define EN_OFF     0              // en[8192] f32: 0.5*||e||^2
#define EFRAG_OFF  32768          // 1 MB frag-ordered fp16 emb (128 B/code)
#define IDX_OFF    32768          // i32 [16384] final indices       (overlay)
#define BEST1_OFF  2129920        // u64 [16][16384] per-(slice,token) best (enc)
#define BEST2_OFF  4227072        // f32 [16][16384] per-(slice,token) 2nd-best
#define CNT_OFF    5275648        // +4: f32 nsum (0.99*sum(cs_in))

__device__ __forceinline__ u64 enc_pair(float s, int idx) {
  u32 u = __float_as_uint(s);
  u = (u & 0x80000000u) ? ~u : (u | 0x80000000u);   // order-preserving
  return ((u64)u << 32) | (u32)(~idx);              // ~idx: ties -> min idx
}
__device__ __forceinline__ float dec_score(u64 e) {
  u32 u = (u32)(e >> 32);
  u = (u & 0x80000000u) ? (u & 0x7fffffffu) : ~u;
  return __uint_as_float(u);
}
__device__ __forceinline__ int dec_idx(u64 e) { return (int)(~(u32)e); }
__device__ __forceinline__ unsigned short f2h(float f) {  // f32 -> fp16 RNE
  union { _Float16 h; unsigned short u; } v;
  v.h = (_Float16)f;
  return v.u;
}
// exact f32 chain (identical FMA order across screen/fixup uses)
__device__ __forceinline__ float exact_dot(const float* __restrict__ sx,
                                           const float* __restrict__ emb, int k) {
  const float4* e = (const float4*)(emb + (size_t)k * 64);
  float a = 0.f;
#pragma unroll
  for (int q = 0; q < 16; ++q) {
    float4 v = e[q];
    a = fmaf(sx[4 * q],     v.x, a);
    a = fmaf(sx[4 * q + 1], v.y, a);
    a = fmaf(sx[4 * q + 2], v.z, a);
    a = fmaf(sx[4 * q + 3], v.w, a);
  }
  return a;
}

// ---- fused prep: [0,512) eprep | [512,1031) init | 1031 solo | [1032,1160) zprep
// eprep: en = 0.5*||e||^2 + emb -> fp16 16x16 B-frags
// init : out5 = 0.99*avg; solo: out4 = 0.99*cs AND nsum (block-local reduce)
// zprep: z_e -> fp16 16x16 A-frags via LDS transpose (coalesced both sides)
__global__ __launch_bounds__(256) void k_prep(const float* __restrict__ emb,
                                              const float* __restrict__ cs_in,
                                              const float* __restrict__ avg_in,
                                              const float* __restrict__ z_e,
                                              float* __restrict__ en,
                                              unsigned char* __restrict__ efrag,
                                              unsigned char* __restrict__ zfrag,
                                              float* __restrict__ out4,
                                              float* __restrict__ out5,
                                              float* __restrict__ nsum) {
  __shared__ float warr[4];
  __shared__ float sx[64][129];       // zprep transpose buffer (33 KB, padded)
  int bid = blockIdx.x;
  int t = threadIdx.x;
  if (bid < 512) {                    // ---- eprep: 131072 float4s of emb
    int tid = bid * 256 + t;
    int k = tid >> 4, q = tid & 15;   // code k, channels 4q..4q+3
    float4 v = ((const float4*)emb)[tid];
    ushort4 hv;
    hv.x = f2h(v.x); hv.y = f2h(v.y); hv.z = f2h(v.z); hv.w = f2h(v.w);
    // tile=k>>4, col=k&15, frag=q>>3, kib=(q>>1)&3, half=q&1
    size_t off = (size_t)(k >> 4) * 2048 + (size_t)(q >> 3) * 1024
               + (size_t)((q >> 1) & 3) * 256 + (size_t)(k & 15) * 16
               + (size_t)(q & 1) * 8;
    *(ushort4*)(efrag + off) = hv;
    float s = v.x * v.x + v.y * v.y + v.z * v.z + v.w * v.w;
    s += __shfl_xor(s, 1, 16);
    s += __shfl_xor(s, 2, 16);
    s += __shfl_xor(s, 4, 16);
    s += __shfl_xor(s, 8, 16);
    if (q == 0) en[k] = 0.5f * s;
  } else if (bid < 1031) {            // ---- init avg: 131072 float4s
    int tid = (bid - 512) * 256 + t;
    if (tid < 131072) {
      float4 v = ((const float4*)avg_in)[tid];
      v.x *= DECAYF; v.y *= DECAYF; v.z *= DECAYF; v.w *= DECAYF;
      ((float4*)out5)[tid] = v;
    }
  } else if (bid == 1031) {           // ---- solo: cs scale + total sum
    float s = 0.f;
#pragma unroll
    for (int q = 0; q < 8; ++q) {
      int idx = q * 256 + t;                   // 2048 float4s of cluster_size
      float4 v = ((const float4*)cs_in)[idx];
      v.x *= DECAYF; v.y *= DECAYF; v.z *= DECAYF; v.w *= DECAYF;
      ((float4*)out4)[idx] = v;
      s += v.x + v.y + v.z + v.w;              // already x0.99
    }
    s += __shfl_xor(s, 1, 64);
    s += __shfl_xor(s, 2, 64);
    s += __shfl_xor(s, 4, 64);
    s += __shfl_xor(s, 8, 64);
    s += __shfl_xor(s, 16, 64);
    s += __shfl_xor(s, 32, 64);
    if ((t & 63) == 0) warr[t >> 6] = s;
    __syncthreads();
    if (t == 0) *nsum = warr[0] + warr[1] + warr[2] + warr[3];
  } else {                            // ---- zprep: 128 blocks x 128 tokens
    int n0 = (bid - 1032) * 128;
    int b = n0 >> 10, hwb = n0 & 1023;
    // coalesced load: 64 ch x 128 floats = 2048 float4s
#pragma unroll
    for (int r = 0; r < 8; ++r) {
      int g = r * 256 + t;                     // 0..2047
      int c = g >> 5, f4 = g & 31;
      float4 v = *(const float4*)(z_e + ((size_t)b << 16) + ((size_t)c << 10)
                                  + hwb + f4 * 4);
      sx[c][f4 * 4 + 0] = v.x;
      sx[c][f4 * 4 + 1] = v.y;
      sx[c][f4 * 4 + 2] = v.z;
      sx[c][f4 * 4 + 3] = v.w;
    }
    __syncthreads();
    // frag write: 128 tokens x 8 cells; one 16-B cell pair per (r,t)
#pragma unroll
    for (int r = 0; r < 4; ++r) {
      int id = r * 256 + t;                    // 0..1023
      int nl = id & 127, k = id >> 7;          // token-local, cell
      int n = n0 + nl;
      unsigned short u[8];
#pragma unroll
      for (int j = 0; j < 8; ++j) u[j] = f2h(sx[k * 8 + j][nl]);
      size_t off = (size_t)(n >> 4) * 2048 + (size_t)(k >> 2) * 1024
                 + (size_t)(k & 3) * 256 + (size_t)(n & 15) * 16;
      *(ushort4*)(zfrag + off)     = make_ushort4(u[0], u[1], u[2], u[3]);
      *(ushort4*)(zfrag + off + 8) = make_ushort4(u[4], u[5], u[6], u[7]);
    }
  }
}

// ---- MFMA argmin: 16x16x32 fp16; 2 token-tiles/wave; 16 slices -----------
// grid 2048 = 128 token-groups (128 tokens) x 16 K-slices (512 codes)
__global__ __launch_bounds__(256) void k_argmin_mfma(
    const unsigned char* __restrict__ zfrag,
    const unsigned char* __restrict__ efrag,
    const float* __restrict__ en, u64* __restrict__ best1,
    float* __restrict__ best2) {
  alignas(16) __shared__ unsigned char sbuf[2][8192];   // dbuf: 4 tiles each
  __shared__ float sen[512];                            // 0.5*||e||^2 slice
  const int tb = blockIdx.x >> 4;            // token group (128 tokens)
  const int sl = blockIdx.x & 15;            // K-slice (512 codes = 32 tiles)
  const int wave = threadIdx.x >> 6, lane = threadIdx.x & 63;
  const int col = lane & 15, g4 = lane >> 4;
  const int token0 = tb * 128 + wave * 32;
  const int scb = sl << 9;

  // en slice -> LDS (512 f32 = 128 float4)
  if (threadIdx.x < 128)
    ((float4*)sen)[threadIdx.x] = ((const float4*)(en + scb))[threadIdx.x];

  // A fragments: 2 token-tiles x 2 K-frags, direct vector loads from zfrag
  f16x8 a[2][2];
  {
    const unsigned char* zb = zfrag + ((size_t)(tb * 8 + wave * 2)) * 2048
                            + (size_t)g4 * 256 + (size_t)col * 16;
    a[0][0] = *(const f16x8*)(zb);
    a[0][1] = *(const f16x8*)(zb + 1024);
    a[1][0] = *(const f16x8*)(zb + 2048);
    a[1][1] = *(const f16x8*)(zb + 3072);
  }
  float b1[8], b2[8];
#pragma unroll
  for (int r = 0; r < 8; ++r) { b1[r] = -3.0e38f; b2[r] = -3.0e38f; }

  const unsigned char* gbase0 = efrag + (size_t)scb * 128;   // 128 B/code
  auto stage = [&](int ib, int buf) {
    const unsigned char* g = gbase0 + (size_t)ib * 8192 + (size_t)wave * 2048;
#pragma unroll
    for (int it = 0; it < 2; ++it) {
      __builtin_amdgcn_global_load_lds(
          (const __attribute__((address_space(1))) u32*)(g + it * 1024 + lane * 16),
          (__attribute__((address_space(3))) u32*)(&sbuf[buf][wave * 2048 + it * 1024]),
          16, 0, 0);
    }
  };
  stage(0, 0);                                // prologue
  for (int ib = 0; ib < 8; ++ib) {
    __syncthreads();                          // drains vmcnt -> stage(ib) done
    if (ib < 7) stage(ib + 1, (ib + 1) & 1);  // prefetch overlaps compute(ib)
    const unsigned char* sb0 = &sbuf[ib & 1][0];
#pragma unroll
    for (int ct = 0; ct < 4; ++ct) {
      const int t = ib * 4 + ct;              // 0..31 tile id in slice
      const float negen = -sen[t * 16 + col]; // this lane's code column
      f16x8 bf0 = *(const f16x8*)(sb0 + ct * 2048 + lane * 16);
      f16x8 bf1 = *(const f16x8*)(sb0 + ct * 2048 + 1024 + lane * 16);
      f32x4 acc0, acc1;
#pragma unroll
      for (int r = 0; r < 4; ++r) { acc0[r] = negen; acc1[r] = negen; }
      acc0 = __builtin_amdgcn_mfma_f32_16x16x32_f16(a[0][0], bf0, acc0, 0, 0, 0);
      acc0 = __builtin_amdgcn_mfma_f32_16x16x32_f16(a[0][1], bf1, acc0, 0, 0, 0);
      acc1 = __builtin_amdgcn_mfma_f32_16x16x32_f16(a[1][0], bf0, acc1, 0, 0, 0);
      acc1 = __builtin_amdgcn_mfma_f32_16x16x32_f16(a[1][1], bf1, acc1, 0, 0, 0);
      const u32 emb6 = (u32)(63 - t);         // tile idx in low 6 mantissa bits
#pragma unroll
      for (int r = 0; r < 4; ++r) {
        float f0 = __uint_as_float((__float_as_uint(acc0[r]) & 0xFFFFFFC0u) | emb6);
        b2[r] = __builtin_amdgcn_fmed3f(f0, b1[r], b2[r]);
        b1[r] = fmaxf(b1[r], f0);
        float f1 = __uint_as_float((__float_as_uint(acc1[r]) & 0xFFFFFFC0u) | emb6);
        b2[4 + r] = __builtin_amdgcn_fmed3f(f1, b1[4 + r], b2[4 + r]);
        b1[4 + r] = fmaxf(b1[4 + r], f1);
      }
    }
  }
  // reduce across the 16 code-columns (lanes within each 16-lane group)
  int mi[8];
#pragma unroll
  for (int r = 0; r < 8; ++r) mi[r] = col;
#pragma unroll
  for (int st = 1; st < 16; st <<= 1) {
#pragma unroll
    for (int r = 0; r < 8; ++r) {
      float ob1 = __shfl_xor(b1[r], st, 64);
      float ob2 = __shfl_xor(b2[r], st, 64);
      int omi = __shfl_xor(mi[r], st, 64);
      bool ogt = ob1 > b1[r];            // strict: equal -> quantized tie -> fixup
      b2[r] = fmaxf(fminf(b1[r], ob1), fmaxf(b2[r], ob2));
      mi[r] = ogt ? omi : mi[r];
      b1[r] = fmaxf(b1[r], ob1);
    }
  }
  if (col == 0) {   // lanes 0,16,32,48: 8 token-rows each; [sl][token] layout
#pragma unroll
    for (int r = 0; r < 8; ++r) {
      int tt = r >> 2, rr = r & 3;
      int token = token0 + tt * 16 + g4 * 4 + rr;   // C/D row map [m89]
      int t = 63 - (int)(__float_as_uint(b1[r]) & 63u);
      int gcode = scb + t * 16 + mi[r];
      best1[(size_t)sl * 16384 + token] = enc_pair(b1[r], gcode);
      best2[(size_t)sl * 16384 + token] = b2[r];
    }
  }
}

// ---- merged resolve + candidate fixup: block = 64 tokens -----------------
// Phase A: per-token top/second/flag; write idxa. Phase B: flagged tokens
// get exact f32 candidates (per-slice best >= theta) + rare full-slice scan.
// Rigor: |exact-screened|<=eps, TAU>=2*eps => true argmin in candidate set.
__global__ __launch_bounds__(256) void k_resfix(const float* __restrict__ z_e,
                                                const float* __restrict__ emb,
                                                const float* __restrict__ en,
                                                const u64* __restrict__ best1,
                                                const float* __restrict__ best2,
                                                int* __restrict__ idxa) {
  __shared__ float sxr[64];
  __shared__ int flist[64];
  __shared__ float fth[64];
  __shared__ int nflag;
  __shared__ u32 fmask;
  __shared__ u64 red;
  int t = threadIdx.x;
  int n0 = blockIdx.x * 64;
  if (t == 0) nflag = 0;
  __syncthreads();
  if (t < 64) {
    int n = n0 + t;
    u64 e[16];
#pragma unroll
    for (int s = 0; s < 16; ++s) e[s] = best1[(size_t)s * 16384 + n];
    u64 top = e[0];
#pragma unroll
    for (int s = 1; s < 16; ++s) top = e[s] > top ? e[s] : top;
    float second = -3.0e38f;
#pragma unroll
    for (int s = 0; s < 16; ++s)
      second = fmaxf(second, best2[(size_t)s * 16384 + n]);
#pragma unroll
    for (int s = 0; s < 16; ++s)
      if (e[s] != top) second = fmaxf(second, dec_score(e[s]));
    idxa[n] = dec_idx(top);
    if (dec_score(top) - second < TAU) {
      int p = atomicAdd(&nflag, 1);
      flist[p] = n;
      fth[p] = dec_score(top);
    }
  }
  __syncthreads();
  int nf = nflag;
  for (int i = 0; i < nf; ++i) {
    int n = flist[i];
    float theta = fth[i] - TAU;
    if (t == 0) { fmask = 0; red = 0ull; }
    if (t < 64) {
      sxr[t] = z_e[((size_t)(n >> 10) << 16) + ((size_t)t << 10) + (n & 1023)];
    }
    __syncthreads();
    u64 myb = 0ull;
    if (t < 16) {
      u64 es = best1[(size_t)t * 16384 + n];
      if (best2[(size_t)t * 16384 + n] >= theta) atomicOr(&fmask, 1u << t);
      if (dec_score(es) >= theta) {        // candidate: exact dot
        int k = dec_idx(es);
        float a = exact_dot(sxr, emb, k) - en[k];
        myb = enc_pair(a, k);
      }
    }
    __syncthreads();
    u32 fm = fmask;
    while (fm) {                           // rare: full 512-code slice rescan
      int s = __ffs(fm) - 1;
      fm &= fm - 1;
      int k0 = (s << 9) + t;               // 2 codes: +0, +256
      float a0 = exact_dot(sxr, emb, k0)       - en[k0];
      float a1 = exact_dot(sxr, emb, k0 + 256) - en[k0 + 256];
      u64 m0 = enc_pair(a0, k0), m1 = enc_pair(a1, k0 + 256);
      u64 mm = m0 > m1 ? m0 : m1;
      myb = mm > myb ? mm : myb;
    }
    if (myb) atomicMax(&red, myb);
    __syncthreads();
    if (t == 0) idxa[n] = dec_idx(red);
    __syncthreads();
  }
}

// ---- scatter EMA stats: LDS-transposed coalesced reads + per-token atomics
__global__ __launch_bounds__(256) void k_scatter(const float* __restrict__ z_e,
                                                 const int* __restrict__ idxa,
                                                 float* __restrict__ out4,
                                                 float* __restrict__ out5) {
  __shared__ float sx[64][129];
  int t = threadIdx.x;
  int n0 = blockIdx.x * 128;                  // 128 blocks x 128 tokens
  int b = n0 >> 10, hwb = n0 & 1023;
#pragma unroll
  for (int r = 0; r < 8; ++r) {
    int g = r * 256 + t;                      // 0..2047 float4s
    int c = g >> 5, f4 = g & 31;
    float4 v = *(const float4*)(z_e + ((size_t)b << 16) + ((size_t)c << 10)
                                + hwb + f4 * 4);
    sx[c][f4 * 4 + 0] = v.x;
    sx[c][f4 * 4 + 1] = v.y;
    sx[c][f4 * 4 + 2] = v.z;
    sx[c][f4 * 4 + 3] = v.w;
  }
  __syncthreads();
  int wave = t >> 6, lane = t & 63;
#pragma unroll
  for (int i = 0; i < 32; ++i) {
    int tok = wave * 32 + i;
    int idx = idxa[n0 + tok];
    atomicAdd(out5 + (size_t)idx * 64 + lane, OMDF * sx[lane][tok]);
    if (lane == 0) atomicAdd(out4 + idx, OMDF);
  }
}

// ---- gather z_q / z_q_st / indices --------------------------------------
__global__ __launch_bounds__(256) void k_gather(const float* __restrict__ z_e,
                                                const float* __restrict__ emb,
                                                const int* __restrict__ idxa,
                                                float* __restrict__ out0,
                                                float* __restrict__ out1,
                                                float* __restrict__ out2) {
  int tid = blockIdx.x * 256 + threadIdx.x;   // 262144 = 16 b x 64 c x 256 hw4
  int hw4 = tid & 255;
  int c   = (tid >> 8) & 63;
  int b   = tid >> 14;
  int n0  = (b << 10) + (hw4 << 2);
  size_t off = ((size_t)b << 16) + ((size_t)c << 10) + ((size_t)hw4 << 2);
  float4 z = *(const float4*)(z_e + off);
  int i0 = idxa[n0], i1 = idxa[n0 + 1], i2 = idxa[n0 + 2], i3 = idxa[n0 + 3];
  float4 q;
  q.x = emb[(size_t)i0 * 64 + c];
  q.y = emb[(size_t)i1 * 64 + c];
  q.z = emb[(size_t)i2 * 64 + c];
  q.w = emb[(size_t)i3 * 64 + c];
  float4 st;
  st.x = z.x + (q.x - z.x);
  st.y = z.y + (q.y - z.y);
  st.z = z.z + (q.z - z.z);
  st.w = z.w + (q.w - z.w);
  *(float4*)(out2 + off) = q;
  *(float4*)(out0 + off) = st;
  if (c == 0) {
    float4 f = make_float4((float)i0, (float)i1, (float)i2, (float)i3);
    *(float4*)(out1 + n0) = f;
  }
}

// ---- new_embedding = new_embedding_avg / cs -----------------------------
__global__ __launch_bounds__(256) void k_final(const float* __restrict__ out4,
                                               const float* __restrict__ out5,
                                               const float* __restrict__ nsum,
                                               float* __restrict__ out3) {
  int tid = blockIdx.x * 256 + threadIdx.x;
  int k = tid >> 4;
  double nn  = (double)*nsum + 163.84;
  double ncs = (double)out4[k];
  double cs  = (ncs + 1e-5) / (nn + 8192.0 * 1e-5) * nn;
  float inv  = (float)(1.0 / cs);
  float4 v = ((const float4*)out5)[tid];
  v.x *= inv; v.y *= inv; v.z *= inv; v.w *= inv;
  ((float4*)out3)[tid] = v;
}

extern "C" void kernel_launch(void* const* d_in, const int* in_sizes, int n_in,
                              void* d_out, int out_size, void* d_ws, size_t ws_size,
                              hipStream_t stream) {
  const float* z_e    = (const float*)d_in[0];
  const float* emb    = (const float*)d_in[1];
  const float* cs_in  = (const float*)d_in[2];
  const float* avg_in = (const float*)d_in[3];

  float* out  = (float*)d_out;
  float* out0 = out;                    // z_q_st        1048576
  float* out1 = out0 + 1048576;         // indices(f32)  16384
  float* out2 = out1 + 16384;           // z_q           1048576
  float* out3 = out2 + 1048576;         // new_embedding 524288
  float* out4 = out3 + 524288;          // new_cluster   8192
  float* out5 = out4 + 8192;            // new_emb_avg   524288

  char* ws = (char*)d_ws;
  float* en            = (float*)(ws + EN_OFF);
  unsigned char* efrag = (unsigned char*)(ws + EFRAG_OFF);
  u64* best1           = (u64*)(ws + BEST1_OFF);
  float* best2         = (float*)(ws + BEST2_OFF);
  int* idxa            = (int*)(ws + IDX_OFF);
  float* nsum          = (float*)(ws + CNT_OFF + 4);
  unsigned char* zfrag = (unsigned char*)out0;   // 2 MB scratch in out0 region

  k_prep       <<<1160, 256, 0, stream>>>(emb, cs_in, avg_in, z_e, en, efrag,
                                          zfrag, out4, out5, nsum);
  k_argmin_mfma<<<2048, 256, 0, stream>>>(zfrag, efrag, en, best1, best2);
  k_resfix     <<<256,  256, 0, stream>>>(z_e, emb, en, best1, best2, idxa);
  k_scatter    <<<128,  256, 0, stream>>>(z_e, idxa, out4, out5);
  k_gather     <<<1024, 256, 0, stream>>>(z_e, emb, idxa, out0, out1, out2);
  k_final      <<<512,  256, 0, stream>>>(out4, out5, nsum, out3);
}

// Round 10
// 147.259 us; speedup vs baseline: 1.0285x; 1.0285x over previous
//
#include <hip/hip_runtime.h>

// Problem: B=16,C=64,H=32,W=32 -> N=16384 tokens; K=8192 codes.
#define DECAYF 0.99f
#define OMDF   0.01f
#define TAU    3.5e-2f   // fp16 screen: ~9-sigma pairwise (sigma~3.8e-3); candidate fixup exact f32

typedef unsigned int u32;
typedef unsigned long long u64;
typedef __attribute__((ext_vector_type(8))) _Float16 f16x8;  // 8 fp16 (4 VGPRs)
typedef __attribute__((ext_vector_type(4))) float f32x4;     // MFMA 16x16 acc

// ws layout (bytes). High-water = 5275656 (== R0 proven size).
// zfrag (2 MB, fp16 z_e in 16x16 A-frag order) lives in the out0 output
// region: written by k_prep, read by k_argmin, overwritten by k_gather.
// IDX overlays EFRAG (efrag dead after k_argmin; stream-ordered).
#define EN_OFF     0              // en[8192] f32: 0.5*||e||^2
#define EFRAG_OFF  32768          // 1 MB frag-ordered fp16 emb (128 B/code)
#define IDX_OFF    32768          // i32 [16384] final indices       (overlay)
#define BEST1_OFF  2129920        // u64 [16][16384] per-(slice,token) best (enc)
#define BEST2_OFF  4227072        // f32 [16][16384] per-(slice,token) 2nd-best
#define CNT_OFF    5275648        // +4: f32 nsum (0.99*sum(cs_in))

__device__ __forceinline__ u64 enc_pair(float s, int idx) {
  u32 u = __float_as_uint(s);
  u = (u & 0x80000000u) ? ~u : (u | 0x80000000u);   // order-preserving
  return ((u64)u << 32) | (u32)(~idx);              // ~idx: ties -> min idx
}
__device__ __forceinline__ float dec_score(u64 e) {
  u32 u = (u32)(e >> 32);
  u = (u & 0x80000000u) ? (u & 0x7fffffffu) : ~u;
  return __uint_as_float(u);
}
__device__ __forceinline__ int dec_idx(u64 e) { return (int)(~(u32)e); }
__device__ __forceinline__ unsigned short f2h(float f) {  // f32 -> fp16 RNE
  union { _Float16 h; unsigned short u; } v;
  v.h = (_Float16)f;
  return v.u;
}
// exact f32 chain (identical FMA order across screen/fixup uses)
__device__ __forceinline__ float exact_dot(const float* __restrict__ sx,
                                           const float* __restrict__ emb, int k) {
  const float4* e = (const float4*)(emb + (size_t)k * 64);
  float a = 0.f;
#pragma unroll
  for (int q = 0; q < 16; ++q) {
    float4 v = e[q];
    a = fmaf(sx[4 * q],     v.x, a);
    a = fmaf(sx[4 * q + 1], v.y, a);
    a = fmaf(sx[4 * q + 2], v.z, a);
    a = fmaf(sx[4 * q + 3], v.w, a);
  }
  return a;
}

// ---- fused prep: [0,512) eprep | [512,1031) init | 1031 solo | [1032,1160) zprep
__global__ __launch_bounds__(256) void k_prep(const float* __restrict__ emb,
                                              const float* __restrict__ cs_in,
                                              const float* __restrict__ avg_in,
                                              const float* __restrict__ z_e,
                                              float* __restrict__ en,
                                              unsigned char* __restrict__ efrag,
                                              unsigned char* __restrict__ zfrag,
                                              float* __restrict__ out4,
                                              float* __restrict__ out5,
                                              float* __restrict__ nsum) {
  __shared__ float warr[4];
  __shared__ float sx[64][129];       // zprep transpose buffer (33 KB, padded)
  int bid = blockIdx.x;
  int t = threadIdx.x;
  if (bid < 512) {                    // ---- eprep: 131072 float4s of emb
    int tid = bid * 256 + t;
    int k = tid >> 4, q = tid & 15;   // code k, channels 4q..4q+3
    float4 v = ((const float4*)emb)[tid];
    ushort4 hv;
    hv.x = f2h(v.x); hv.y = f2h(v.y); hv.z = f2h(v.z); hv.w = f2h(v.w);
    // tile=k>>4, col=k&15, frag=q>>3, kib=(q>>1)&3, half=q&1
    size_t off = (size_t)(k >> 4) * 2048 + (size_t)(q >> 3) * 1024
               + (size_t)((q >> 1) & 3) * 256 + (size_t)(k & 15) * 16
               + (size_t)(q & 1) * 8;
    *(ushort4*)(efrag + off) = hv;
    float s = v.x * v.x + v.y * v.y + v.z * v.z + v.w * v.w;
    s += __shfl_xor(s, 1, 16);
    s += __shfl_xor(s, 2, 16);
    s += __shfl_xor(s, 4, 16);
    s += __shfl_xor(s, 8, 16);
    if (q == 0) en[k] = 0.5f * s;
  } else if (bid < 1031) {            // ---- init avg: 131072 float4s
    int tid = (bid - 512) * 256 + t;
    if (tid < 131072) {
      float4 v = ((const float4*)avg_in)[tid];
      v.x *= DECAYF; v.y *= DECAYF; v.z *= DECAYF; v.w *= DECAYF;
      ((float4*)out5)[tid] = v;
    }
  } else if (bid == 1031) {           // ---- solo: cs scale + total sum
    float s = 0.f;
#pragma unroll
    for (int q = 0; q < 8; ++q) {
      int idx = q * 256 + t;                   // 2048 float4s of cluster_size
      float4 v = ((const float4*)cs_in)[idx];
      v.x *= DECAYF; v.y *= DECAYF; v.z *= DECAYF; v.w *= DECAYF;
      ((float4*)out4)[idx] = v;
      s += v.x + v.y + v.z + v.w;              // already x0.99
    }
    s += __shfl_xor(s, 1, 64);
    s += __shfl_xor(s, 2, 64);
    s += __shfl_xor(s, 4, 64);
    s += __shfl_xor(s, 8, 64);
    s += __shfl_xor(s, 16, 64);
    s += __shfl_xor(s, 32, 64);
    if ((t & 63) == 0) warr[t >> 6] = s;
    __syncthreads();
    if (t == 0) *nsum = warr[0] + warr[1] + warr[2] + warr[3];
  } else {                            // ---- zprep: 128 blocks x 128 tokens
    int n0 = (bid - 1032) * 128;
    int b = n0 >> 10, hwb = n0 & 1023;
#pragma unroll
    for (int r = 0; r < 8; ++r) {
      int g = r * 256 + t;                     // 0..2047 float4s, coalesced
      int c = g >> 5, f4 = g & 31;
      float4 v = *(const float4*)(z_e + ((size_t)b << 16) + ((size_t)c << 10)
                                  + hwb + f4 * 4);
      sx[c][f4 * 4 + 0] = v.x;
      sx[c][f4 * 4 + 1] = v.y;
      sx[c][f4 * 4 + 2] = v.z;
      sx[c][f4 * 4 + 3] = v.w;
    }
    __syncthreads();
#pragma unroll
    for (int r = 0; r < 4; ++r) {
      int id = r * 256 + t;                    // 0..1023
      int nl = id & 127, k = id >> 7;          // token-local, cell
      int n = n0 + nl;
      unsigned short u[8];
#pragma unroll
      for (int j = 0; j < 8; ++j) u[j] = f2h(sx[k * 8 + j][nl]);
      size_t off = (size_t)(n >> 4) * 2048 + (size_t)(k >> 2) * 1024
                 + (size_t)(k & 3) * 256 + (size_t)(n & 15) * 16;
      *(ushort4*)(zfrag + off)     = make_ushort4(u[0], u[1], u[2], u[3]);
      *(ushort4*)(zfrag + off + 8) = make_ushort4(u[4], u[5], u[6], u[7]);
    }
  }
}

// ---- MFMA argmin: 16x16x32 fp16; 4 token-tiles/wave; NO LDS staging ------
// B frags streamed L2->regs, 2-deep static prefetch; zero main-loop barriers.
// grid 1024 = (256 token-groups of 64) x 16 slices; wave = one (tg, sl).
__global__ __launch_bounds__(256) void k_argmin_mfma(
    const unsigned char* __restrict__ zfrag,
    const unsigned char* __restrict__ efrag,
    const float* __restrict__ en, u64* __restrict__ best1,
    float* __restrict__ best2) {
  __shared__ float sen[512];                 // 0.5*||e||^2 slice
  const int sl = blockIdx.x & 15;            // K-slice (512 codes = 32 tiles)
  const int wave = threadIdx.x >> 6, lane = threadIdx.x & 63;
  const int tg = (blockIdx.x >> 4) * 4 + wave;   // 64-token group
  const int col = lane & 15, g4 = lane >> 4;
  const int scb = sl << 9;

  if (threadIdx.x < 128)
    ((float4*)sen)[threadIdx.x] = ((const float4*)(en + scb))[threadIdx.x];
  __syncthreads();                           // only barrier in the kernel

  // A fragments: 4 token-tiles x 2 K-frags from zfrag
  f16x8 a[4][2];
  {
    const unsigned char* zb = zfrag + (size_t)(tg * 4) * 2048
                            + (size_t)g4 * 256 + (size_t)col * 16;
#pragma unroll
    for (int tt = 0; tt < 4; ++tt) {
      a[tt][0] = *(const f16x8*)(zb + tt * 2048);
      a[tt][1] = *(const f16x8*)(zb + tt * 2048 + 1024);
    }
  }
  float b1[16], b2[16];
#pragma unroll
  for (int r = 0; r < 16; ++r) { b1[r] = -3.0e38f; b2[r] = -3.0e38f; }

  const unsigned char* gb = efrag + (size_t)scb * 128 + (size_t)lane * 16;

  auto body = [&](int t, f16x8 u0, f16x8 u1) {
    const float negen = -sen[t * 16 + col];  // this lane's code column
    f32x4 acc0, acc1, acc2, acc3;
#pragma unroll
    for (int r = 0; r < 4; ++r) { acc0[r] = negen; acc1[r] = negen;
                                  acc2[r] = negen; acc3[r] = negen; }
    acc0 = __builtin_amdgcn_mfma_f32_16x16x32_f16(a[0][0], u0, acc0, 0, 0, 0);
    acc1 = __builtin_amdgcn_mfma_f32_16x16x32_f16(a[1][0], u0, acc1, 0, 0, 0);
    acc2 = __builtin_amdgcn_mfma_f32_16x16x32_f16(a[2][0], u0, acc2, 0, 0, 0);
    acc3 = __builtin_amdgcn_mfma_f32_16x16x32_f16(a[3][0], u0, acc3, 0, 0, 0);
    acc0 = __builtin_amdgcn_mfma_f32_16x16x32_f16(a[0][1], u1, acc0, 0, 0, 0);
    acc1 = __builtin_amdgcn_mfma_f32_16x16x32_f16(a[1][1], u1, acc1, 0, 0, 0);
    acc2 = __builtin_amdgcn_mfma_f32_16x16x32_f16(a[2][1], u1, acc2, 0, 0, 0);
    acc3 = __builtin_amdgcn_mfma_f32_16x16x32_f16(a[3][1], u1, acc3, 0, 0, 0);
    const u32 emb6 = (u32)(63 - t);          // tile idx in low 6 mantissa bits
#pragma unroll
    for (int r = 0; r < 4; ++r) {
      float f0 = __uint_as_float((__float_as_uint(acc0[r]) & 0xFFFFFFC0u) | emb6);
      b2[r] = __builtin_amdgcn_fmed3f(f0, b1[r], b2[r]);
      b1[r] = fmaxf(b1[r], f0);
      float f1 = __uint_as_float((__float_as_uint(acc1[r]) & 0xFFFFFFC0u) | emb6);
      b2[4 + r] = __builtin_amdgcn_fmed3f(f1, b1[4 + r], b2[4 + r]);
      b1[4 + r] = fmaxf(b1[4 + r], f1);
      float f2 = __uint_as_float((__float_as_uint(acc2[r]) & 0xFFFFFFC0u) | emb6);
      b2[8 + r] = __builtin_amdgcn_fmed3f(f2, b1[8 + r], b2[8 + r]);
      b1[8 + r] = fmaxf(b1[8 + r], f2);
      float f3 = __uint_as_float((__float_as_uint(acc3[r]) & 0xFFFFFFC0u) | emb6);
      b2[12 + r] = __builtin_amdgcn_fmed3f(f3, b1[12 + r], b2[12 + r]);
      b1[12 + r] = fmaxf(b1[12 + r], f3);
    }
  };

  // 2-deep static-register prefetch pipeline, unroll-by-2 (no dyn-indexed regs)
  f16x8 c0 = *(const f16x8*)(gb);
  f16x8 c1 = *(const f16x8*)(gb + 1024);
  f16x8 d0 = *(const f16x8*)(gb + 2048);
  f16x8 d1 = *(const f16x8*)(gb + 3072);
  for (int t = 0; t < 32; t += 2) {
    f16x8 u0 = c0, u1 = c1;
    if (t + 2 < 32) {
      c0 = *(const f16x8*)(gb + (size_t)(t + 2) * 2048);
      c1 = *(const f16x8*)(gb + (size_t)(t + 2) * 2048 + 1024);
    }
    body(t, u0, u1);
    u0 = d0; u1 = d1;
    if (t + 3 < 32) {
      d0 = *(const f16x8*)(gb + (size_t)(t + 3) * 2048);
      d1 = *(const f16x8*)(gb + (size_t)(t + 3) * 2048 + 1024);
    }
    body(t + 1, u0, u1);
  }

  // reduce across the 16 code-columns (lanes within each 16-lane group)
  int mi[16];
#pragma unroll
  for (int r = 0; r < 16; ++r) mi[r] = col;
#pragma unroll
  for (int st = 1; st < 16; st <<= 1) {
#pragma unroll
    for (int r = 0; r < 16; ++r) {
      float ob1 = __shfl_xor(b1[r], st, 64);
      float ob2 = __shfl_xor(b2[r], st, 64);
      int omi = __shfl_xor(mi[r], st, 64);
      bool ogt = ob1 > b1[r];            // strict: equal -> quantized tie -> fixup
      b2[r] = fmaxf(fminf(b1[r], ob1), fmaxf(b2[r], ob2));
      mi[r] = ogt ? omi : mi[r];
      b1[r] = fmaxf(b1[r], ob1);
    }
  }
  if (col == 0) {   // lanes 0,16,32,48: 16 token-rows each; [sl][token] layout
#pragma unroll
    for (int r = 0; r < 16; ++r) {
      int tt = r >> 2, rr = r & 3;
      int token = tg * 64 + tt * 16 + g4 * 4 + rr;   // C/D row map [m89]
      int t = 63 - (int)(__float_as_uint(b1[r]) & 63u);
      int gcode = scb + t * 16 + mi[r];
      best1[(size_t)sl * 16384 + token] = enc_pair(b1[r], gcode);
      best2[(size_t)sl * 16384 + token] = b2[r];
    }
  }
}

// ---- merged resolve + candidate fixup: block = 64 tokens -----------------
__global__ __launch_bounds__(256) void k_resfix(const float* __restrict__ z_e,
                                                const float* __restrict__ emb,
                                                const float* __restrict__ en,
                                                const u64* __restrict__ best1,
                                                const float* __restrict__ best2,
                                                int* __restrict__ idxa) {
  __shared__ float sxr[64];
  __shared__ int flist[64];
  __shared__ float fth[64];
  __shared__ int nflag;
  __shared__ u32 fmask;
  __shared__ u64 red;
  int t = threadIdx.x;
  int n0 = blockIdx.x * 64;
  if (t == 0) nflag = 0;
  __syncthreads();
  if (t < 64) {
    int n = n0 + t;
    u64 e[16];
#pragma unroll
    for (int s = 0; s < 16; ++s) e[s] = best1[(size_t)s * 16384 + n];
    u64 top = e[0];
#pragma unroll
    for (int s = 1; s < 16; ++s) top = e[s] > top ? e[s] : top;
    float second = -3.0e38f;
#pragma unroll
    for (int s = 0; s < 16; ++s)
      second = fmaxf(second, best2[(size_t)s * 16384 + n]);
#pragma unroll
    for (int s = 0; s < 16; ++s)
      if (e[s] != top) second = fmaxf(second, dec_score(e[s]));
    idxa[n] = dec_idx(top);
    if (dec_score(top) - second < TAU) {
      int p = atomicAdd(&nflag, 1);
      flist[p] = n;
      fth[p] = dec_score(top);
    }
  }
  __syncthreads();
  int nf = nflag;
  for (int i = 0; i < nf; ++i) {
    int n = flist[i];
    float theta = fth[i] - TAU;
    if (t == 0) { fmask = 0; red = 0ull; }
    if (t < 64) {
      sxr[t] = z_e[((size_t)(n >> 10) << 16) + ((size_t)t << 10) + (n & 1023)];
    }
    __syncthreads();
    u64 myb = 0ull;
    if (t < 16) {
      u64 es = best1[(size_t)t * 16384 + n];
      if (best2[(size_t)t * 16384 + n] >= theta) atomicOr(&fmask, 1u << t);
      if (dec_score(es) >= theta) {        // candidate: exact dot
        int k = dec_idx(es);
        float a = exact_dot(sxr, emb, k) - en[k];
        myb = enc_pair(a, k);
      }
    }
    __syncthreads();
    u32 fm = fmask;
    while (fm) {                           // rare: full 512-code slice rescan
      int s = __ffs(fm) - 1;
      fm &= fm - 1;
      int k0 = (s << 9) + t;               // 2 codes: +0, +256
      float a0 = exact_dot(sxr, emb, k0)       - en[k0];
      float a1 = exact_dot(sxr, emb, k0 + 256) - en[k0 + 256];
      u64 m0 = enc_pair(a0, k0), m1 = enc_pair(a1, k0 + 256);
      u64 mm = m0 > m1 ? m0 : m1;
      myb = mm > myb ? mm : myb;
    }
    if (myb) atomicMax(&red, myb);
    __syncthreads();
    if (t == 0) idxa[n] = dec_idx(red);
    __syncthreads();
  }
}

// ---- scatter EMA stats (lane = channel -> coalesced atomics; R8-proven) --
__global__ __launch_bounds__(256) void k_scatter(const float* __restrict__ z_e,
                                                 const int* __restrict__ idxa,
                                                 float* __restrict__ out4,
                                                 float* __restrict__ out5) {
  int tid = blockIdx.x * 256 + threadIdx.x;   // 1M = 16384 tokens x 64 ch
  int n = tid >> 6, c = tid & 63;
  int idx = idxa[n];
  int b = n >> 10, hw = n & 1023;
  float x = z_e[((size_t)b << 16) + ((size_t)c << 10) + hw];
  atomicAdd(out5 + (size_t)idx * 64 + c, OMDF * x);
  if (c == 0) atomicAdd(out4 + idx, OMDF);
}

// ---- gather z_q / z_q_st / indices --------------------------------------
__global__ __launch_bounds__(256) void k_gather(const float* __restrict__ z_e,
                                                const float* __restrict__ emb,
                                                const int* __restrict__ idxa,
                                                float* __restrict__ out0,
                                                float* __restrict__ out1,
                                                float* __restrict__ out2) {
  int tid = blockIdx.x * 256 + threadIdx.x;   // 262144 = 16 b x 64 c x 256 hw4
  int hw4 = tid & 255;
  int c   = (tid >> 8) & 63;
  int b   = tid >> 14;
  int n0  = (b << 10) + (hw4 << 2);
  size_t off = ((size_t)b << 16) + ((size_t)c << 10) + ((size_t)hw4 << 2);
  float4 z = *(const float4*)(z_e + off);
  int i0 = idxa[n0], i1 = idxa[n0 + 1], i2 = idxa[n0 + 2], i3 = idxa[n0 + 3];
  float4 q;
  q.x = emb[(size_t)i0 * 64 + c];
  q.y = emb[(size_t)i1 * 64 + c];
  q.z = emb[(size_t)i2 * 64 + c];
  q.w = emb[(size_t)i3 * 64 + c];
  float4 st;
  st.x = z.x + (q.x - z.x);
  st.y = z.y + (q.y - z.y);
  st.z = z.z + (q.z - z.z);
  st.w = z.w + (q.w - z.w);
  *(float4*)(out2 + off) = q;
  *(float4*)(out0 + off) = st;
  if (c == 0) {
    float4 f = make_float4((float)i0, (float)i1, (float)i2, (float)i3);
    *(float4*)(out1 + n0) = f;
  }
}

// ---- new_embedding = new_embedding_avg / cs -----------------------------
__global__ __launch_bounds__(256) void k_final(const float* __restrict__ out4,
                                               const float* __restrict__ out5,
                                               const float* __restrict__ nsum,
                                               float* __restrict__ out3) {
  int tid = blockIdx.x * 256 + threadIdx.x;
  int k = tid >> 4;
  double nn  = (double)*nsum + 163.84;
  double ncs = (double)out4[k];
  double cs  = (ncs + 1e-5) / (nn + 8192.0 * 1e-5) * nn;
  float inv  = (float)(1.0 / cs);
  float4 v = ((const float4*)out5)[tid];
  v.x *= inv; v.y *= inv; v.z *= inv; v.w *= inv;
  ((float4*)out3)[tid] = v;
}

extern "C" void kernel_launch(void* const* d_in, const int* in_sizes, int n_in,
                              void* d_out, int out_size, void* d_ws, size_t ws_size,
                              hipStream_t stream) {
  const float* z_e    = (const float*)d_in[0];
  const float* emb    = (const float*)d_in[1];
  const float* cs_in  = (const float*)d_in[2];
  const float* avg_in = (const float*)d_in[3];

  float* out  = (float*)d_out;
  float* out0 = out;                    // z_q_st        1048576
  float* out1 = out0 + 1048576;         // indices(f32)  16384
  float* out2 = out1 + 16384;           // z_q           1048576
  float* out3 = out2 + 1048576;         // new_embedding 524288
  float* out4 = out3 + 524288;          // new_cluster   8192
  float* out5 = out4 + 8192;            // new_emb_avg   524288

  char* ws = (char*)d_ws;
  float* en            = (float*)(ws + EN_OFF);
  unsigned char* efrag = (unsigned char*)(ws + EFRAG_OFF);
  u64* best1           = (u64*)(ws + BEST1_OFF);
  float* best2         = (float*)(ws + BEST2_OFF);
  int* idxa            = (int*)(ws + IDX_OFF);
  float* nsum          = (float*)(ws + CNT_OFF + 4);
  unsigned char* zfrag = (unsigned char*)out0;   // 2 MB scratch in out0 region

  k_prep       <<<1160, 256, 0, stream>>>(emb, cs_in, avg_in, z_e, en, efrag,
                                          zfrag, out4, out5, nsum);
  k_argmin_mfma<<<1024, 256, 0, stream>>>(zfrag, efrag, en, best1, best2);
  k_resfix     <<<256,  256, 0, stream>>>(z_e, emb, en, best1, best2, idxa);
  k_scatter    <<<4096, 256, 0, stream>>>(z_e, idxa, out4, out5);
  k_gather     <<<1024, 256, 0, stream>>>(z_e, emb, idxa, out0, out1, out2);
  k_final      <<<512,  256, 0, stream>>>(out4, out5, nsum, out3);
}

// Round 11
// 145.857 us; speedup vs baseline: 1.0384x; 1.0096x over previous
//
#include <hip/hip_runtime.h>

// Problem: B=16,C=64,H=32,W=32 -> N=16384 tokens; K=8192 codes.
#define DECAYF 0.99f
#define OMDF   0.01f
#define TAU    3.5e-2f   // fp16 screen: ~9-sigma pairwise (sigma~3.8e-3); candidate fixup exact f32

typedef unsigned int u32;
typedef unsigned long long u64;
typedef __attribute__((ext_vector_type(8))) _Float16 f16x8;  // 8 fp16 (4 VGPRs)
typedef __attribute__((ext_vector_type(4))) float f32x4;     // MFMA 16x16 acc

// ws layout (bytes). High-water = 5275656 (== R0 proven size).
// zfrag (2 MB, fp16 z_e in 16x16 A-frag order) lives in the out0 output
// region: written by k_prep, read by k_argmin, overwritten by k_gather.
// IDX overlays EFRAG (efrag dead after k_argmin; stream-ordered).
#define EN_OFF     0              // en[8192] f32: 0.5*||e||^2
#define EFRAG_OFF  32768          // 1 MB frag-ordered fp16 emb (128 B/code)
#define IDX_OFF    32768          // i32 [16384] final indices       (overlay)
#define BEST1_OFF  2129920        // u64 [16][16384] per-(slice,token) best (enc)
#define BEST2_OFF  4227072        // f32 [16][16384] per-(slice,token) 2nd-best
#define CNT_OFF    5275648        // +4: f32 nsum (0.99*sum(cs_in))

__device__ __forceinline__ u64 enc_pair(float s, int idx) {
  u32 u = __float_as_uint(s);
  u = (u & 0x80000000u) ? ~u : (u | 0x80000000u);   // order-preserving
  return ((u64)u << 32) | (u32)(~idx);              // ~idx: ties -> min idx
}
__device__ __forceinline__ float dec_score(u64 e) {
  u32 u = (u32)(e >> 32);
  u = (u & 0x80000000u) ? (u & 0x7fffffffu) : ~u;
  return __uint_as_float(u);
}
__device__ __forceinline__ int dec_idx(u64 e) { return (int)(~(u32)e); }
__device__ __forceinline__ unsigned short f2h(float f) {  // f32 -> fp16 RNE
  union { _Float16 h; unsigned short u; } v;
  v.h = (_Float16)f;
  return v.u;
}
// exact f32 chain (identical FMA order across screen/fixup uses)
__device__ __forceinline__ float exact_dot(const float* __restrict__ sx,
                                           const float* __restrict__ emb, int k) {
  const float4* e = (const float4*)(emb + (size_t)k * 64);
  float a = 0.f;
#pragma unroll
  for (int q = 0; q < 16; ++q) {
    float4 v = e[q];
    a = fmaf(sx[4 * q],     v.x, a);
    a = fmaf(sx[4 * q + 1], v.y, a);
    a = fmaf(sx[4 * q + 2], v.z, a);
    a = fmaf(sx[4 * q + 3], v.w, a);
  }
  return a;
}

// ---- fused prep: [0,512) eprep | [512,1031) init | 1031 solo | [1032,1160) zprep
__global__ __launch_bounds__(256) void k_prep(const float* __restrict__ emb,
                                              const float* __restrict__ cs_in,
                                              const float* __restrict__ avg_in,
                                              const float* __restrict__ z_e,
                                              float* __restrict__ en,
                                              unsigned char* __restrict__ efrag,
                                              unsigned char* __restrict__ zfrag,
                                              float* __restrict__ out4,
                                              float* __restrict__ out5,
                                              float* __restrict__ nsum) {
  __shared__ float warr[4];
  __shared__ float sx[64][129];       // zprep transpose buffer (33 KB, padded)
  int bid = blockIdx.x;
  int t = threadIdx.x;
  if (bid < 512) {                    // ---- eprep: 131072 float4s of emb
    int tid = bid * 256 + t;
    int k = tid >> 4, q = tid & 15;   // code k, channels 4q..4q+3
    float4 v = ((const float4*)emb)[tid];
    ushort4 hv;
    hv.x = f2h(v.x); hv.y = f2h(v.y); hv.z = f2h(v.z); hv.w = f2h(v.w);
    // tile=k>>4, col=k&15, frag=q>>3, kib=(q>>1)&3, half=q&1
    size_t off = (size_t)(k >> 4) * 2048 + (size_t)(q >> 3) * 1024
               + (size_t)((q >> 1) & 3) * 256 + (size_t)(k & 15) * 16
               + (size_t)(q & 1) * 8;
    *(ushort4*)(efrag + off) = hv;
    float s = v.x * v.x + v.y * v.y + v.z * v.z + v.w * v.w;
    s += __shfl_xor(s, 1, 16);
    s += __shfl_xor(s, 2, 16);
    s += __shfl_xor(s, 4, 16);
    s += __shfl_xor(s, 8, 16);
    if (q == 0) en[k] = 0.5f * s;
  } else if (bid < 1031) {            // ---- init avg: 131072 float4s
    int tid = (bid - 512) * 256 + t;
    if (tid < 131072) {
      float4 v = ((const float4*)avg_in)[tid];
      v.x *= DECAYF; v.y *= DECAYF; v.z *= DECAYF; v.w *= DECAYF;
      ((float4*)out5)[tid] = v;
    }
  } else if (bid == 1031) {           // ---- solo: cs scale + total sum
    float s = 0.f;
#pragma unroll
    for (int q = 0; q < 8; ++q) {
      int idx = q * 256 + t;                   // 2048 float4s of cluster_size
      float4 v = ((const float4*)cs_in)[idx];
      v.x *= DECAYF; v.y *= DECAYF; v.z *= DECAYF; v.w *= DECAYF;
      ((float4*)out4)[idx] = v;
      s += v.x + v.y + v.z + v.w;              // already x0.99
    }
    s += __shfl_xor(s, 1, 64);
    s += __shfl_xor(s, 2, 64);
    s += __shfl_xor(s, 4, 64);
    s += __shfl_xor(s, 8, 64);
    s += __shfl_xor(s, 16, 64);
    s += __shfl_xor(s, 32, 64);
    if ((t & 63) == 0) warr[t >> 6] = s;
    __syncthreads();
    if (t == 0) *nsum = warr[0] + warr[1] + warr[2] + warr[3];
  } else {                            // ---- zprep: 128 blocks x 128 tokens
    int n0 = (bid - 1032) * 128;
    int b = n0 >> 10, hwb = n0 & 1023;
#pragma unroll
    for (int r = 0; r < 8; ++r) {
      int g = r * 256 + t;                     // 0..2047 float4s, coalesced
      int c = g >> 5, f4 = g & 31;
      float4 v = *(const float4*)(z_e + ((size_t)b << 16) + ((size_t)c << 10)
                                  + hwb + f4 * 4);
      sx[c][f4 * 4 + 0] = v.x;
      sx[c][f4 * 4 + 1] = v.y;
      sx[c][f4 * 4 + 2] = v.z;
      sx[c][f4 * 4 + 3] = v.w;
    }
    __syncthreads();
#pragma unroll
    for (int r = 0; r < 4; ++r) {
      int id = r * 256 + t;                    // 0..1023
      int nl = id & 127, k = id >> 7;          // token-local, cell
      int n = n0 + nl;
      unsigned short u[8];
#pragma unroll
      for (int j = 0; j < 8; ++j) u[j] = f2h(sx[k * 8 + j][nl]);
      size_t off = (size_t)(n >> 4) * 2048 + (size_t)(k >> 2) * 1024
                 + (size_t)(k & 3) * 256 + (size_t)(n & 15) * 16;
      *(ushort4*)(zfrag + off)     = make_ushort4(u[0], u[1], u[2], u[3]);
      *(ushort4*)(zfrag + off + 8) = make_ushort4(u[4], u[5], u[6], u[7]);
    }
  }
}

// ---- MFMA argmin: 16x16x32 fp16; 2 token-tiles/wave; NO LDS staging ------
// B frags streamed L2->regs, 2-deep static prefetch; zero main-loop barriers.
// grid 2048 = (512 groups of 32 tokens) x 16 slices -> 8 blk/CU resident.
__global__ __launch_bounds__(256) void k_argmin_mfma(
    const unsigned char* __restrict__ zfrag,
    const unsigned char* __restrict__ efrag,
    const float* __restrict__ en, u64* __restrict__ best1,
    float* __restrict__ best2) {
  __shared__ float sen[512];                 // 0.5*||e||^2 slice
  const int sl = blockIdx.x & 15;            // K-slice (512 codes = 32 tiles)
  const int wave = threadIdx.x >> 6, lane = threadIdx.x & 63;
  const int tg = (blockIdx.x >> 4) * 4 + wave;   // 32-token group [0,512)
  const int col = lane & 15, g4 = lane >> 4;
  const int scb = sl << 9;

  if (threadIdx.x < 128)
    ((float4*)sen)[threadIdx.x] = ((const float4*)(en + scb))[threadIdx.x];
  __syncthreads();                           // only barrier in the kernel

  // A fragments: 2 token-tiles x 2 K-frags from zfrag
  f16x8 a[2][2];
  {
    const unsigned char* zb = zfrag + (size_t)(tg * 2) * 2048
                            + (size_t)g4 * 256 + (size_t)col * 16;
    a[0][0] = *(const f16x8*)(zb);
    a[0][1] = *(const f16x8*)(zb + 1024);
    a[1][0] = *(const f16x8*)(zb + 2048);
    a[1][1] = *(const f16x8*)(zb + 3072);
  }
  float b1[8], b2[8];
#pragma unroll
  for (int r = 0; r < 8; ++r) { b1[r] = -3.0e38f; b2[r] = -3.0e38f; }

  const unsigned char* gb = efrag + (size_t)scb * 128 + (size_t)lane * 16;

  auto body = [&](int t, f16x8 u0, f16x8 u1) {
    const float negen = -sen[t * 16 + col];  // this lane's code column
    f32x4 acc0, acc1;
#pragma unroll
    for (int r = 0; r < 4; ++r) { acc0[r] = negen; acc1[r] = negen; }
    acc0 = __builtin_amdgcn_mfma_f32_16x16x32_f16(a[0][0], u0, acc0, 0, 0, 0);
    acc1 = __builtin_amdgcn_mfma_f32_16x16x32_f16(a[1][0], u0, acc1, 0, 0, 0);
    acc0 = __builtin_amdgcn_mfma_f32_16x16x32_f16(a[0][1], u1, acc0, 0, 0, 0);
    acc1 = __builtin_amdgcn_mfma_f32_16x16x32_f16(a[1][1], u1, acc1, 0, 0, 0);
    const u32 emb6 = (u32)(63 - t);          // tile idx in low 6 mantissa bits
#pragma unroll
    for (int r = 0; r < 4; ++r) {
      float f0 = __uint_as_float((__float_as_uint(acc0[r]) & 0xFFFFFFC0u) | emb6);
      b2[r] = __builtin_amdgcn_fmed3f(f0, b1[r], b2[r]);
      b1[r] = fmaxf(b1[r], f0);
      float f1 = __uint_as_float((__float_as_uint(acc1[r]) & 0xFFFFFFC0u) | emb6);
      b2[4 + r] = __builtin_amdgcn_fmed3f(f1, b1[4 + r], b2[4 + r]);
      b1[4 + r] = fmaxf(b1[4 + r], f1);
    }
  };

  // 2-deep static-register prefetch pipeline, unroll-by-2 (no dyn-indexed regs)
  f16x8 c0 = *(const f16x8*)(gb);
  f16x8 c1 = *(const f16x8*)(gb + 1024);
  f16x8 d0 = *(const f16x8*)(gb + 2048);
  f16x8 d1 = *(const f16x8*)(gb + 3072);
  for (int t = 0; t < 32; t += 2) {
    f16x8 u0 = c0, u1 = c1;
    if (t + 2 < 32) {
      c0 = *(const f16x8*)(gb + (size_t)(t + 2) * 2048);
      c1 = *(const f16x8*)(gb + (size_t)(t + 2) * 2048 + 1024);
    }
    body(t, u0, u1);
    u0 = d0; u1 = d1;
    if (t + 3 < 32) {
      d0 = *(const f16x8*)(gb + (size_t)(t + 3) * 2048);
      d1 = *(const f16x8*)(gb + (size_t)(t + 3) * 2048 + 1024);
    }
    body(t + 1, u0, u1);
  }

  // reduce across the 16 code-columns (lanes within each 16-lane group)
  int mi[8];
#pragma unroll
  for (int r = 0; r < 8; ++r) mi[r] = col;
#pragma unroll
  for (int st = 1; st < 16; st <<= 1) {
#pragma unroll
    for (int r = 0; r < 8; ++r) {
      float ob1 = __shfl_xor(b1[r], st, 64);
      float ob2 = __shfl_xor(b2[r], st, 64);
      int omi = __shfl_xor(mi[r], st, 64);
      bool ogt = ob1 > b1[r];            // strict: equal -> quantized tie -> fixup
      b2[r] = fmaxf(fminf(b1[r], ob1), fmaxf(b2[r], ob2));
      mi[r] = ogt ? omi : mi[r];
      b1[r] = fmaxf(b1[r], ob1);
    }
  }
  if (col == 0) {   // lanes 0,16,32,48: 8 token-rows each; [sl][token] layout
#pragma unroll
    for (int r = 0; r < 8; ++r) {
      int tt = r >> 2, rr = r & 3;
      int token = tg * 32 + tt * 16 + g4 * 4 + rr;   // C/D row map [m89]
      int t = 63 - (int)(__float_as_uint(b1[r]) & 63u);
      int gcode = scb + t * 16 + mi[r];
      best1[(size_t)sl * 16384 + token] = enc_pair(b1[r], gcode);
      best2[(size_t)sl * 16384 + token] = b2[r];
    }
  }
}

// ---- merged resolve + candidate fixup: block = 64 tokens -----------------
__global__ __launch_bounds__(256) void k_resfix(const float* __restrict__ z_e,
                                                const float* __restrict__ emb,
                                                const float* __restrict__ en,
                                                const u64* __restrict__ best1,
                                                const float* __restrict__ best2,
                                                int* __restrict__ idxa) {
  __shared__ float sxr[64];
  __shared__ int flist[64];
  __shared__ float fth[64];
  __shared__ int nflag;
  __shared__ u32 fmask;
  __shared__ u64 red;
  int t = threadIdx.x;
  int n0 = blockIdx.x * 64;
  if (t == 0) nflag = 0;
  __syncthreads();
  if (t < 64) {
    int n = n0 + t;
    u64 e[16];
#pragma unroll
    for (int s = 0; s < 16; ++s) e[s] = best1[(size_t)s * 16384 + n];
    u64 top = e[0];
#pragma unroll
    for (int s = 1; s < 16; ++s) top = e[s] > top ? e[s] : top;
    float second = -3.0e38f;
#pragma unroll
    for (int s = 0; s < 16; ++s)
      second = fmaxf(second, best2[(size_t)s * 16384 + n]);
#pragma unroll
    for (int s = 0; s < 16; ++s)
      if (e[s] != top) second = fmaxf(second, dec_score(e[s]));
    idxa[n] = dec_idx(top);
    if (dec_score(top) - second < TAU) {
      int p = atomicAdd(&nflag, 1);
      flist[p] = n;
      fth[p] = dec_score(top);
    }
  }
  __syncthreads();
  int nf = nflag;
  for (int i = 0; i < nf; ++i) {
    int n = flist[i];
    float theta = fth[i] - TAU;
    if (t == 0) { fmask = 0; red = 0ull; }
    if (t < 64) {
      sxr[t] = z_e[((size_t)(n >> 10) << 16) + ((size_t)t << 10) + (n & 1023)];
    }
    __syncthreads();
    u64 myb = 0ull;
    if (t < 16) {
      u64 es = best1[(size_t)t * 16384 + n];
      if (best2[(size_t)t * 16384 + n] >= theta) atomicOr(&fmask, 1u << t);
      if (dec_score(es) >= theta) {        // candidate: exact dot
        int k = dec_idx(es);
        float a = exact_dot(sxr, emb, k) - en[k];
        myb = enc_pair(a, k);
      }
    }
    __syncthreads();
    u32 fm = fmask;
    while (fm) {                           // rare: full 512-code slice rescan
      int s = __ffs(fm) - 1;
      fm &= fm - 1;
      int k0 = (s << 9) + t;               // 2 codes: +0, +256
      float a0 = exact_dot(sxr, emb, k0)       - en[k0];
      float a1 = exact_dot(sxr, emb, k0 + 256) - en[k0 + 256];
      u64 m0 = enc_pair(a0, k0), m1 = enc_pair(a1, k0 + 256);
      u64 mm = m0 > m1 ? m0 : m1;
      myb = mm > myb ? mm : myb;
    }
    if (myb) atomicMax(&red, myb);
    __syncthreads();
    if (t == 0) idxa[n] = dec_idx(red);
    __syncthreads();
  }
}

// ---- gather z_q / z_q_st / indices + EMA scatter phase -------------------
// Phase A: gather (original proven mapping). Phase B: scatter with the
// proven lane=channel mapping (wave = 64 channels of one token) - the two
// phases are independent (both need only idxa) so fusion is safe.
__global__ __launch_bounds__(256) void k_gather(const float* __restrict__ z_e,
                                                const float* __restrict__ emb,
                                                const int* __restrict__ idxa,
                                                float* __restrict__ out0,
                                                float* __restrict__ out1,
                                                float* __restrict__ out2,
                                                float* __restrict__ out4,
                                                float* __restrict__ out5) {
  int tid = blockIdx.x * 256 + threadIdx.x;   // 262144 = 16 b x 64 c x 256 hw4
  {   // ---- phase A: gather
    int hw4 = tid & 255;
    int c   = (tid >> 8) & 63;
    int b   = tid >> 14;
    int n0  = (b << 10) + (hw4 << 2);
    size_t off = ((size_t)b << 16) + ((size_t)c << 10) + ((size_t)hw4 << 2);
    float4 z = *(const float4*)(z_e + off);
    int i0 = idxa[n0], i1 = idxa[n0 + 1], i2 = idxa[n0 + 2], i3 = idxa[n0 + 3];
    float4 q;
    q.x = emb[(size_t)i0 * 64 + c];
    q.y = emb[(size_t)i1 * 64 + c];
    q.z = emb[(size_t)i2 * 64 + c];
    q.w = emb[(size_t)i3 * 64 + c];
    float4 st;
    st.x = z.x + (q.x - z.x);
    st.y = z.y + (q.y - z.y);
    st.z = z.z + (q.z - z.z);
    st.w = z.w + (q.w - z.w);
    *(float4*)(out2 + off) = q;
    *(float4*)(out0 + off) = st;
    if (c == 0) {
      float4 f = make_float4((float)i0, (float)i1, (float)i2, (float)i3);
      *(float4*)(out1 + n0) = f;
    }
  }
  {   // ---- phase B: scatter (4 tokens/thread, lane = channel)
    int c = tid & 63;
    int nb = (tid >> 6) * 4;
#pragma unroll
    for (int i = 0; i < 4; ++i) {
      int n = nb + i;
      int idx = idxa[n];
      int b = n >> 10, hw = n & 1023;
      float x = z_e[((size_t)b << 16) + ((size_t)c << 10) + hw];
      atomicAdd(out5 + (size_t)idx * 64 + c, OMDF * x);
      if (c == 0) atomicAdd(out4 + idx, OMDF);
    }
  }
}

// ---- new_embedding = new_embedding_avg / cs -----------------------------
__global__ __launch_bounds__(256) void k_final(const float* __restrict__ out4,
                                               const float* __restrict__ out5,
                                               const float* __restrict__ nsum,
                                               float* __restrict__ out3) {
  int tid = blockIdx.x * 256 + threadIdx.x;
  int k = tid >> 4;
  double nn  = (double)*nsum + 163.84;
  double ncs = (double)out4[k];
  double cs  = (ncs + 1e-5) / (nn + 8192.0 * 1e-5) * nn;
  float inv  = (float)(1.0 / cs);
  float4 v = ((const float4*)out5)[tid];
  v.x *= inv; v.y *= inv; v.z *= inv; v.w *= inv;
  ((float4*)out3)[tid] = v;
}

extern "C" void kernel_launch(void* const* d_in, const int* in_sizes, int n_in,
                              void* d_out, int out_size, void* d_ws, size_t ws_size,
                              hipStream_t stream) {
  const float* z_e    = (const float*)d_in[0];
  const float* emb    = (const float*)d_in[1];
  const float* cs_in  = (const float*)d_in[2];
  const float* avg_in = (const float*)d_in[3];

  float* out  = (float*)d_out;
  float* out0 = out;                    // z_q_st        1048576
  float* out1 = out0 + 1048576;         // indices(f32)  16384
  float* out2 = out1 + 16384;           // z_q           1048576
  float* out3 = out2 + 1048576;         // new_embedding 524288
  float* out4 = out3 + 524288;          // new_cluster   8192
  float* out5 = out4 + 8192;            // new_emb_avg   524288

  char* ws = (char*)d_ws;
  float* en            = (float*)(ws + EN_OFF);
  unsigned char* efrag = (unsigned char*)(ws + EFRAG_OFF);
  u64* best1           = (u64*)(ws + BEST1_OFF);
  float* best2         = (float*)(ws + BEST2_OFF);
  int* idxa            = (int*)(ws + IDX_OFF);
  float* nsum          = (float*)(ws + CNT_OFF + 4);
  unsigned char* zfrag = (unsigned char*)out0;   // 2 MB scratch in out0 region

  k_prep       <<<1160, 256, 0, stream>>>(emb, cs_in, avg_in, z_e, en, efrag,
                                          zfrag, out4, out5, nsum);
  k_argmin_mfma<<<2048, 256, 0, stream>>>(zfrag, efrag, en, best1, best2);
  k_resfix     <<<256,  256, 0, stream>>>(z_e, emb, en, best1, best2, idxa);
  k_gather     <<<1024, 256, 0, stream>>>(z_e, emb, idxa, out0, out1, out2,
                                          out4, out5);
  k_final      <<<512,  256, 0, stream>>>(out4, out5, nsum, out3);
}